// Round 1
// baseline (2891.499 us; speedup 1.0000x reference)
//
#include <hip/hip_runtime.h>
#include <cstdint>
#include <cstddef>

#define B_   32
#define WN   64
#define NT   50
#define C_   384
#define NH   12
#define HD   32
#define SCALE 0.17677669529663687f  // 32^-0.5

typedef float  f32x4  __attribute__((ext_vector_type(4)));
typedef __bf16 bf16x8 __attribute__((ext_vector_type(8)));

__device__ __forceinline__ float bf2f(unsigned short u) {
  union { unsigned int u; float f; } v; v.u = ((unsigned int)u) << 16; return v.f;
}
__device__ __forceinline__ unsigned short f2bf(float f) {
  union { float f; unsigned int u; } v; v.f = f;
  unsigned int r = v.u + 0x7FFFu + ((v.u >> 16) & 1u);  // RNE
  return (unsigned short)(r >> 16);
}

// ---------------- fp32 -> bf16 conversion ----------------
__global__ __launch_bounds__(256) void cvt_bf16_k(const float* __restrict__ src,
                                                  unsigned short* __restrict__ dst,
                                                  int nquad) {
  int i = blockIdx.x * 256 + threadIdx.x;
  if (i < nquad) {
    float4 v = ((const float4*)src)[i];
    ushort4 o;
    o.x = f2bf(v.x); o.y = f2bf(v.y); o.z = f2bf(v.z); o.w = f2bf(v.w);
    ((ushort4*)dst)[i] = o;
  }
}

// ---- bf16 MFMA GEMM: Out[M][N] = A[M][K] @ W[N][K]^T (+bias) ----
// 64x64 tile, 4 waves each computing 32x32 via 2x2 mfma_f32_16x16x32_bf16.
template<bool OUT_BF16, bool HAS_BIAS>
__global__ __launch_bounds__(256) void gemm_bf16_k(
    const unsigned short* __restrict__ A,
    const unsigned short* __restrict__ W,
    const float* __restrict__ bias,
    void* __restrict__ Out, int M, int N, int K)
{
  __shared__ unsigned short As[64][40];  // stride 40 -> 16B-aligned rows, 2-way max conflict
  __shared__ unsigned short Bs[64][40];
  const int n0 = blockIdx.x * 64;
  const int m0 = blockIdx.y * 64;
  const int t  = threadIdx.x;
  const int srow = t >> 2;
  const int sseg = (t & 3) << 3;
  const int lane = t & 63;
  const int wv = t >> 6;
  const int wm = (wv >> 1) << 5;
  const int wn = (wv & 1) << 5;
  const int lr = lane & 15;
  const int kq = (lane >> 4) << 3;

  f32x4 acc[2][2] = {{{0.f,0.f,0.f,0.f},{0.f,0.f,0.f,0.f}},
                     {{0.f,0.f,0.f,0.f},{0.f,0.f,0.f,0.f}}};

  const int nkb = K >> 5;
  for (int kb = 0; kb < nkb; ++kb) {
    const int k0 = kb << 5;
    *(uint4*)&As[srow][sseg] = *(const uint4*)(A + (size_t)(m0 + srow) * K + k0 + sseg);
    *(uint4*)&Bs[srow][sseg] = *(const uint4*)(W + (size_t)(n0 + srow) * K + k0 + sseg);
    __syncthreads();
    bf16x8 a0 = *(const bf16x8*)&As[wm + lr][kq];
    bf16x8 a1 = *(const bf16x8*)&As[wm + 16 + lr][kq];
    bf16x8 b0 = *(const bf16x8*)&Bs[wn + lr][kq];
    bf16x8 b1 = *(const bf16x8*)&Bs[wn + 16 + lr][kq];
    acc[0][0] = __builtin_amdgcn_mfma_f32_16x16x32_bf16(a0, b0, acc[0][0], 0, 0, 0);
    acc[0][1] = __builtin_amdgcn_mfma_f32_16x16x32_bf16(a0, b1, acc[0][1], 0, 0, 0);
    acc[1][0] = __builtin_amdgcn_mfma_f32_16x16x32_bf16(a1, b0, acc[1][0], 0, 0, 0);
    acc[1][1] = __builtin_amdgcn_mfma_f32_16x16x32_bf16(a1, b1, acc[1][1], 0, 0, 0);
    __syncthreads();
  }
  const int orow = (lane >> 4) << 2;
#pragma unroll
  for (int i = 0; i < 2; ++i)
#pragma unroll
    for (int j = 0; j < 2; ++j)
#pragma unroll
      for (int r = 0; r < 4; ++r) {
        int gm = m0 + wm + i * 16 + orow + r;
        int gn = n0 + wn + j * 16 + lr;
        float v = acc[i][j][r];
        if (HAS_BIAS) v += bias[gn];
        if (OUT_BF16) ((unsigned short*)Out)[(size_t)gm * N + gn] = f2bf(v);
        else          ((float*)Out)[(size_t)gm * N + gn] = v;
      }
}

// ---- window attention: per (b,w,h), 50 tokens, d=32; out = softmax(qk^T*s)@v + x ----
__global__ __launch_bounds__(64) void attn_win_k(
    const unsigned short* __restrict__ qkv,
    const float* __restrict__ x,
    unsigned short* __restrict__ outA)
{
  const int h = blockIdx.x;
  const int w = blockIdx.y;
  const int b = blockIdx.z;
  const int t = threadIdx.x;

  __shared__ float qs[64][32];   // XOR-swizzled: col ^= ((row>>3)&7)<<2
  __shared__ float ks[64][32];
  __shared__ float vs[52][32];
  __shared__ float S[64][64];    // XOR-swizzled

  const size_t qbase = ((size_t)(b * WN + w) * NT) * (3 * C_) + h * HD;
  for (int idx = t; idx < 64 * 32; idx += 64) {
    int n = idx >> 5, dd = idx & 31;
    int sw = dd ^ (((n >> 3) & 7) << 2);
    float qv = 0.f, kv = 0.f;
    if (n < NT) {
      qv = bf2f(qkv[qbase + (size_t)n * (3 * C_) + dd]);
      kv = bf2f(qkv[qbase + (size_t)n * (3 * C_) + C_ + dd]);
    }
    qs[n][sw] = qv;
    ks[n][sw] = kv;
    if (n < 52) vs[n][dd] = (n < NT) ? bf2f(qkv[qbase + (size_t)n * (3 * C_) + 2 * C_ + dd]) : 0.f;
  }
  __syncthreads();

  const int ti = t >> 3, tj = t & 7;
  const int i0 = ti << 3, j0 = tj << 3;
  const int swi = ti << 2, swj = tj << 2;
  {
    float acc[8][8];
#pragma unroll
    for (int r = 0; r < 8; ++r)
#pragma unroll
      for (int c = 0; c < 8; ++c) acc[r][c] = 0.f;
#pragma unroll
    for (int d0 = 0; d0 < 32; d0 += 4) {
      float4 qv[8], kv[8];
#pragma unroll
      for (int r = 0; r < 8; ++r) qv[r] = *(const float4*)&qs[i0 + r][d0 ^ swi];
#pragma unroll
      for (int c = 0; c < 8; ++c) kv[c] = *(const float4*)&ks[j0 + c][d0 ^ swj];
#pragma unroll
      for (int r = 0; r < 8; ++r)
#pragma unroll
        for (int c = 0; c < 8; ++c)
          acc[r][c] += qv[r].x * kv[c].x + qv[r].y * kv[c].y + qv[r].z * kv[c].z + qv[r].w * kv[c].w;
    }
#pragma unroll
    for (int r = 0; r < 8; ++r)
#pragma unroll
      for (int c4 = 0; c4 < 2; ++c4) {
        float4 o;
        o.x = acc[r][c4 * 4 + 0] * SCALE; o.y = acc[r][c4 * 4 + 1] * SCALE;
        o.z = acc[r][c4 * 4 + 2] * SCALE; o.w = acc[r][c4 * 4 + 3] * SCALE;
        *(float4*)&S[i0 + r][(j0 + c4 * 4) ^ swi] = o;
      }
  }
  __syncthreads();

  if (t < NT) {
    const int sw = (t >> 3) << 2;
    float m = -1e30f;
    for (int j = 0; j < NT; ++j) m = fmaxf(m, S[t][j ^ sw]);
    float sum = 0.f;
    for (int j = 0; j < NT; ++j) { float e = __expf(S[t][j ^ sw] - m); S[t][j ^ sw] = e; sum += e; }
    float inv = 1.f / sum;
    for (int j = 0; j < NT; ++j) S[t][j ^ sw] *= inv;
    S[t][50 ^ sw] = 0.f;
    S[t][51 ^ sw] = 0.f;
  }
  __syncthreads();

  {
    const int dd0 = tj << 2;
    float oacc[8][4];
#pragma unroll
    for (int r = 0; r < 8; ++r)
#pragma unroll
      for (int c = 0; c < 4; ++c) oacc[r][c] = 0.f;
#pragma unroll
    for (int jv = 0; jv < 52; jv += 4) {
      float4 pv[8];
#pragma unroll
      for (int r = 0; r < 8; ++r) pv[r] = *(const float4*)&S[i0 + r][jv ^ swi];
      float4 vv[4];
#pragma unroll
      for (int jj = 0; jj < 4; ++jj) vv[jj] = *(const float4*)&vs[jv + jj][dd0];
#pragma unroll
      for (int r = 0; r < 8; ++r) {
        oacc[r][0] += pv[r].x * vv[0].x + pv[r].y * vv[1].x + pv[r].z * vv[2].x + pv[r].w * vv[3].x;
        oacc[r][1] += pv[r].x * vv[0].y + pv[r].y * vv[1].y + pv[r].z * vv[2].y + pv[r].w * vv[3].y;
        oacc[r][2] += pv[r].x * vv[0].z + pv[r].y * vv[1].z + pv[r].z * vv[2].z + pv[r].w * vv[3].z;
        oacc[r][3] += pv[r].x * vv[0].w + pv[r].y * vv[1].w + pv[r].z * vv[2].w + pv[r].w * vv[3].w;
      }
    }
    const size_t obase = ((size_t)(b * WN + w) * NT) * C_ + h * HD;
#pragma unroll
    for (int r = 0; r < 8; ++r) {
      int i = i0 + r;
      if (i < NT) {
#pragma unroll
        for (int c = 0; c < 4; ++c) {
          int dd = dd0 + c;
          float val = oacc[r][c] + x[obase + (size_t)i * C_ + dd];
          outA[obase + (size_t)i * C_ + dd] = f2bf(val);
        }
      }
    }
  }
}

// ---- LN + exact GELU on window tokens ----
__global__ __launch_bounds__(64) void ln_gelu_k(
    const unsigned short* __restrict__ outA,
    const float* __restrict__ g, const float* __restrict__ beta,
    unsigned short* __restrict__ wt)
{
  const int row = blockIdx.x;  // 2048 = b*64+w
  const int t = threadIdx.x;
  const size_t base = (size_t)row * NT * C_;  // token 0
  float v[6];
  float s = 0.f, s2 = 0.f;
#pragma unroll
  for (int i = 0; i < 6; ++i) {
    float xv = bf2f(outA[base + t + i * 64]);
    v[i] = xv; s += xv; s2 += xv * xv;
  }
#pragma unroll
  for (int off = 1; off < 64; off <<= 1) {
    s  += __shfl_xor(s, off);
    s2 += __shfl_xor(s2, off);
  }
  const float mu = s * (1.f / 384.f);
  const float var = s2 * (1.f / 384.f) - mu * mu;
  const float rinv = rsqrtf(var + 1e-5f);
#pragma unroll
  for (int i = 0; i < 6; ++i) {
    int c = t + i * 64;
    float y = (v[i] - mu) * rinv * g[c] + beta[c];
    float ge = 0.5f * y * (1.f + erff(y * 0.70710678118654752f));
    wt[(size_t)row * C_ + c] = f2bf(ge);
  }
}

// ---- cross-window pooling attention: pattn[b,h,w,v] ----
__global__ __launch_bounds__(64) void pool_attn_k(
    const float* __restrict__ pqk, float* __restrict__ pattn)
{
  const int h = blockIdx.x;
  const int b = blockIdx.y;
  const int t = threadIdx.x;
  __shared__ float qs[64][32];
  __shared__ float ks[64][32];
  __shared__ float L[64][64];
  for (int idx = t; idx < 64 * 32; idx += 64) {
    int n = idx >> 5, dd = idx & 31;
    int sw = dd ^ (((n >> 3) & 7) << 2);
    size_t base = ((size_t)(b * WN + n)) * (2 * C_) + h * HD + dd;
    qs[n][sw] = pqk[base];
    ks[n][sw] = pqk[base + C_];
  }
  __syncthreads();
  const int ti = t >> 3, tj = t & 7;
  const int i0 = ti << 3, j0 = tj << 3;
  const int swi = ti << 2, swj = tj << 2;
  {
    float acc[8][8];
#pragma unroll
    for (int r = 0; r < 8; ++r)
#pragma unroll
      for (int c = 0; c < 8; ++c) acc[r][c] = 0.f;
#pragma unroll
    for (int d0 = 0; d0 < 32; d0 += 4) {
      float4 qv[8], kv[8];
#pragma unroll
      for (int r = 0; r < 8; ++r) qv[r] = *(const float4*)&qs[i0 + r][d0 ^ swi];
#pragma unroll
      for (int c = 0; c < 8; ++c) kv[c] = *(const float4*)&ks[j0 + c][d0 ^ swj];
#pragma unroll
      for (int r = 0; r < 8; ++r)
#pragma unroll
        for (int c = 0; c < 8; ++c)
          acc[r][c] += qv[r].x * kv[c].x + qv[r].y * kv[c].y + qv[r].z * kv[c].z + qv[r].w * kv[c].w;
    }
#pragma unroll
    for (int r = 0; r < 8; ++r)
#pragma unroll
      for (int c4 = 0; c4 < 2; ++c4) {
        float4 o;
        o.x = acc[r][c4 * 4 + 0] * SCALE; o.y = acc[r][c4 * 4 + 1] * SCALE;
        o.z = acc[r][c4 * 4 + 2] * SCALE; o.w = acc[r][c4 * 4 + 3] * SCALE;
        *(float4*)&L[i0 + r][(j0 + c4 * 4) ^ swi] = o;
      }
  }
  __syncthreads();
  {
    const int sw = (t >> 3) << 2;
    float m = -1e30f;
    for (int j = 0; j < 64; ++j) m = fmaxf(m, L[t][j ^ sw]);
    float sum = 0.f;
    for (int j = 0; j < 64; ++j) { float e = __expf(L[t][j ^ sw] - m); L[t][j ^ sw] = e; sum += e; }
    float inv = 1.f / sum;
    float* dst = pattn + (((size_t)b * NH + h) * 64 + t) * 64;
    for (int j = 0; j < 64; ++j) dst[j] = L[t][j ^ sw] * inv;
  }
}

// ---- pooled SA: psa = pattn @ ax, + ax residual, window->image rearrange, bf16 Y ----
__global__ __launch_bounds__(256) void pool_sa_k(
    const float* __restrict__ pattn,
    const unsigned short* __restrict__ outA,
    unsigned short* __restrict__ Y)
{
  const int tile = blockIdx.x;  // 13 tiles of 128 cols over 49*32=1568
  const int h = blockIdx.y;
  const int b = blockIdx.z;
  const int t = threadIdx.x;
  __shared__ float P[64][65];
  __shared__ float AXT[64][132];
  int limit = 1568 - tile * 128; if (limit > 128) limit = 128;

  {
    const float* src = pattn + ((size_t)b * NH + h) * 4096;
    for (int idx = t; idx < 4096; idx += 256) P[idx >> 6][idx & 63] = src[idx];
  }
  for (int idx = t; idx < 8192; idx += 256) {
    int v = idx >> 7, cc = idx & 127;
    float val = 0.f;
    if (cc < limit) {
      int ch = tile * 128 + cc;
      int s = ch >> 5, dd = ch & 31;
      val = bf2f(outA[((size_t)(b * WN + v) * NT + 1 + s) * C_ + h * HD + dd]);
    }
    AXT[v][cc] = val;
  }
  __syncthreads();

  const int ccq = t & 7;
  const int wi = t >> 3;
  const int w0 = wi, w1 = wi + 32;
  float a0[4][4], a1[4][4];
#pragma unroll
  for (int ch = 0; ch < 4; ++ch)
#pragma unroll
    for (int e = 0; e < 4; ++e) { a0[ch][e] = 0.f; a1[ch][e] = 0.f; }

  for (int v = 0; v < 64; ++v) {
    float p0 = P[w0][v], p1 = P[w1][v];
#pragma unroll
    for (int ch = 0; ch < 4; ++ch) {
      float4 ax = *(const float4*)&AXT[v][ch * 32 + ccq * 4];
      a0[ch][0] += p0 * ax.x; a0[ch][1] += p0 * ax.y; a0[ch][2] += p0 * ax.z; a0[ch][3] += p0 * ax.w;
      a1[ch][0] += p1 * ax.x; a1[ch][1] += p1 * ax.y; a1[ch][2] += p1 * ax.z; a1[ch][3] += p1 * ax.w;
    }
  }
#pragma unroll
  for (int ch = 0; ch < 4; ++ch)
#pragma unroll
    for (int e = 0; e < 4; ++e) {
      int cc = ch * 32 + ccq * 4 + e;
      if (cc < limit) {
        int chd = tile * 128 + cc;
        int s = chd >> 5, dd = chd & 31;
        int srow2 = s / 7, scol = s - srow2 * 7;
        int col = h * HD + dd;
        int hgi = w0 >> 3, wgi = w0 & 7;
        size_t yi = ((size_t)b * 3136 + (hgi * 7 + srow2) * 56 + wgi * 7 + scol) * C_ + col;
        Y[yi] = f2bf(a0[ch][e] + AXT[w0][cc]);
        hgi = w1 >> 3; wgi = w1 & 7;
        yi = ((size_t)b * 3136 + (hgi * 7 + srow2) * 56 + wgi * 7 + scol) * C_ + col;
        Y[yi] = f2bf(a1[ch][e] + AXT[w1][cc]);
      }
    }
}

extern "C" void kernel_launch(void* const* d_in, const int* in_sizes, int n_in,
                              void* d_out, int out_size, void* d_ws, size_t ws_size,
                              hipStream_t stream)
{
  (void)in_sizes; (void)n_in; (void)out_size; (void)ws_size;
  const float* x      = (const float*)d_in[0];
  // d_in[1]=H, d_in[2]=W : fixed at 56 for this problem
  const float* w_qkv  = (const float*)d_in[3];
  const float* w_qk   = (const float*)d_in[4];
  const float* ln_g   = (const float*)d_in[5];
  const float* ln_b   = (const float*)d_in[6];
  const float* w_proj = (const float*)d_in[7];
  const float* b_proj = (const float*)d_in[8];
  float* out = (float*)d_out;

  char* ws = (char*)d_ws;
  size_t off = 0;
  auto alloc = [&](size_t bytes) { size_t o = off; off += (bytes + 255) & ~(size_t)255; return o; };
  const size_t M1 = (size_t)B_ * WN * NT;   // 102400
  const size_t M7 = (size_t)B_ * 3136;      // 100352
  unsigned short* qkv    = (unsigned short*)(ws + alloc(M1 * 1152 * 2));     // 236 MB
  unsigned short* xb     = (unsigned short*)(ws + alloc(M1 * C_ * 2));       // 78.6 MB (aliased by Y later)
  unsigned short* outA   = (unsigned short*)(ws + alloc(M1 * C_ * 2));       // 78.6 MB
  unsigned short* wqkvb  = (unsigned short*)(ws + alloc(1152 * 384 * 2));
  unsigned short* wqkb   = (unsigned short*)(ws + alloc(768 * 384 * 2));
  unsigned short* wprojb = (unsigned short*)(ws + alloc(384 * 384 * 2));
  unsigned short* wt     = (unsigned short*)(ws + alloc(2048 * 384 * 2));
  float* pqk             = (float*)(ws + alloc(2048 * 768 * 4));
  float* pattn           = (float*)(ws + alloc((size_t)B_ * NH * 64 * 64 * 4));
  unsigned short* Y = xb;  // xb dead after QKV GEMM; Y (77.1 MB) fits in its 78.6 MB

  int q;
  q = (int)(M1 * C_ / 4);
  cvt_bf16_k<<<(q + 255) / 256, 256, 0, stream>>>(x, xb, q);
  q = 1152 * 384 / 4;
  cvt_bf16_k<<<(q + 255) / 256, 256, 0, stream>>>(w_qkv, wqkvb, q);
  q = 768 * 384 / 4;
  cvt_bf16_k<<<(q + 255) / 256, 256, 0, stream>>>(w_qk, wqkb, q);
  q = 384 * 384 / 4;
  cvt_bf16_k<<<(q + 255) / 256, 256, 0, stream>>>(w_proj, wprojb, q);

  // 1) qkv = x @ w_qkv^T  (bf16 out)
  gemm_bf16_k<true, false><<<dim3(1152 / 64, M1 / 64), 256, 0, stream>>>(
      xb, wqkvb, nullptr, qkv, (int)M1, 1152, 384);
  // 2) window attention + residual
  attn_win_k<<<dim3(NH, WN, B_), 64, 0, stream>>>(qkv, x, outA);
  // 3) LN + exact GELU on window tokens
  ln_gelu_k<<<2048, 64, 0, stream>>>(outA, ln_g, ln_b, wt);
  // 4) pqk = wt @ w_qk^T (fp32 out)
  gemm_bf16_k<false, false><<<dim3(768 / 64, 2048 / 64), 256, 0, stream>>>(
      wt, wqkb, nullptr, pqk, 2048, 768, 384);
  // 5) cross-window softmax attention
  pool_attn_k<<<dim3(NH, B_), 64, 0, stream>>>(pqk, pattn);
  // 6) psa + ax residual + window->image rearrange (bf16 Y)
  pool_sa_k<<<dim3(13, NH, B_), 256, 0, stream>>>(pattn, outA, Y);
  // 7) out = Y @ w_proj^T + b_proj (fp32)
  gemm_bf16_k<false, true><<<dim3(384 / 64, M7 / 64), 256, 0, stream>>>(
      Y, wprojb, b_proj, out, (int)M7, 384, 384);
}

// Round 2
// 900.560 us; speedup vs baseline: 3.2108x; 3.2108x over previous
//
#include <hip/hip_runtime.h>
#include <cstdint>
#include <cstddef>

#define B_   32
#define WN   64
#define NT   50
#define C_   384
#define NH   12
#define HD   32
#define SCALE 0.17677669529663687f  // 32^-0.5

typedef float  f32x4  __attribute__((ext_vector_type(4)));
typedef __bf16 bf16x8 __attribute__((ext_vector_type(8)));

__device__ __forceinline__ float bf2f(unsigned short u) {
  union { unsigned int u; float f; } v; v.u = ((unsigned int)u) << 16; return v.f;
}
__device__ __forceinline__ unsigned short f2bf(float f) {
  union { float f; unsigned int u; } v; v.f = f;
  unsigned int r = v.u + 0x7FFFu + ((v.u >> 16) & 1u);  // RNE
  return (unsigned short)(r >> 16);
}

// ---------------- fp32 -> bf16 conversion ----------------
__global__ __launch_bounds__(256) void cvt_bf16_k(const float* __restrict__ src,
                                                  unsigned short* __restrict__ dst,
                                                  int nquad) {
  int i = blockIdx.x * 256 + threadIdx.x;
  if (i < nquad) {
    float4 v = ((const float4*)src)[i];
    ushort4 o;
    o.x = f2bf(v.x); o.y = f2bf(v.y); o.z = f2bf(v.z); o.w = f2bf(v.w);
    ((ushort4*)dst)[i] = o;
  }
}

// ---- bf16 MFMA GEMM: Out[M][N] = A[M][K] @ W[N][K]^T (+bias) ----
// 64x64 tile, 4 waves each computing 32x32 via 2x2 mfma_f32_16x16x32_bf16.
template<bool OUT_BF16, bool HAS_BIAS>
__global__ __launch_bounds__(256) void gemm_bf16_k(
    const unsigned short* __restrict__ A,
    const unsigned short* __restrict__ W,
    const float* __restrict__ bias,
    void* __restrict__ Out, int M, int N, int K)
{
  __shared__ unsigned short As[64][40];
  __shared__ unsigned short Bs[64][40];
  const int n0 = blockIdx.x * 64;
  const int m0 = blockIdx.y * 64;
  const int t  = threadIdx.x;
  const int srow = t >> 2;
  const int sseg = (t & 3) << 3;
  const int lane = t & 63;
  const int wv = t >> 6;
  const int wm = (wv >> 1) << 5;
  const int wn = (wv & 1) << 5;
  const int lr = lane & 15;
  const int kq = (lane >> 4) << 3;

  f32x4 acc[2][2] = {{{0.f,0.f,0.f,0.f},{0.f,0.f,0.f,0.f}},
                     {{0.f,0.f,0.f,0.f},{0.f,0.f,0.f,0.f}}};

  const int nkb = K >> 5;
  for (int kb = 0; kb < nkb; ++kb) {
    const int k0 = kb << 5;
    *(uint4*)&As[srow][sseg] = *(const uint4*)(A + (size_t)(m0 + srow) * K + k0 + sseg);
    *(uint4*)&Bs[srow][sseg] = *(const uint4*)(W + (size_t)(n0 + srow) * K + k0 + sseg);
    __syncthreads();
    bf16x8 a0 = *(const bf16x8*)&As[wm + lr][kq];
    bf16x8 a1 = *(const bf16x8*)&As[wm + 16 + lr][kq];
    bf16x8 b0 = *(const bf16x8*)&Bs[wn + lr][kq];
    bf16x8 b1 = *(const bf16x8*)&Bs[wn + 16 + lr][kq];
    acc[0][0] = __builtin_amdgcn_mfma_f32_16x16x32_bf16(a0, b0, acc[0][0], 0, 0, 0);
    acc[0][1] = __builtin_amdgcn_mfma_f32_16x16x32_bf16(a0, b1, acc[0][1], 0, 0, 0);
    acc[1][0] = __builtin_amdgcn_mfma_f32_16x16x32_bf16(a1, b0, acc[1][0], 0, 0, 0);
    acc[1][1] = __builtin_amdgcn_mfma_f32_16x16x32_bf16(a1, b1, acc[1][1], 0, 0, 0);
    __syncthreads();
  }
  const int orow = (lane >> 4) << 2;
#pragma unroll
  for (int i = 0; i < 2; ++i)
#pragma unroll
    for (int j = 0; j < 2; ++j)
#pragma unroll
      for (int r = 0; r < 4; ++r) {
        int gm = m0 + wm + i * 16 + orow + r;
        int gn = n0 + wn + j * 16 + lr;
        float v = acc[i][j][r];
        if (HAS_BIAS) v += bias[gn];
        if (OUT_BF16) ((unsigned short*)Out)[(size_t)gm * N + gn] = f2bf(v);
        else          ((float*)Out)[(size_t)gm * N + gn] = v;
      }
}

// ---- window attention (MFMA): one block per window, all 12 heads ----
// out = softmax(QK^T * s) @ V + x, written bf16 to outA.
__global__ __launch_bounds__(256) void attn_win_k(
    const unsigned short* __restrict__ qkv,
    const float* __restrict__ x,
    unsigned short* __restrict__ outA)
{
  const int w = blockIdx.x, b = blockIdx.y;
  const int t = threadIdx.x;
  const int lane = t & 63, wv = t >> 6;
  const int ln = lane & 15, hi = lane >> 4;

  __shared__ unsigned short Qs[64][40];  // [token][d], pad 40: A-frag reads 2-way max
  __shared__ unsigned short Ks[64][40];  // [token][d], B operand for S
  __shared__ unsigned short Vt[32][72];  // [d][token], A operand for O^T
  __shared__ unsigned short Ps[64][72];  // [q][token], B operand for O^T

  const size_t win = (size_t)(b * WN + w);
  const size_t qkvbase = win * NT * 1152;
  const size_t obase = win * NT * C_;

  for (int h = 0; h < NH; ++h) {
    __syncthreads();  // prior head's LDS reads complete before overwrite
    {
      const int n = t >> 2, seg = (t & 3) << 3;  // token, d-offset (0/8/16/24)
      uint4 qv = {0,0,0,0}, kv = {0,0,0,0}, vv = {0,0,0,0};
      if (n < NT) {
        const unsigned short* p = qkv + qkvbase + (size_t)n * 1152 + h * HD + seg;
        qv = *(const uint4*)p;
        kv = *(const uint4*)(p + C_);
        vv = *(const uint4*)(p + 2 * C_);
      }
      *(uint4*)&Qs[n][seg] = qv;
      *(uint4*)&Ks[n][seg] = kv;
      const unsigned short* vs = (const unsigned short*)&vv;
#pragma unroll
      for (int j = 0; j < 8; ++j) Vt[seg + j][n] = vs[j];  // transpose
    }
    __syncthreads();

    // S = Q K^T for this wave's q-tile (rows wv*16..+16), k = d = 32 (one block)
    f32x4 s[4];
    {
      bf16x8 aq = *(const bf16x8*)&Qs[wv * 16 + ln][hi * 8];
#pragma unroll
      for (int nt = 0; nt < 4; ++nt) {
        bf16x8 bk = *(const bf16x8*)&Ks[nt * 16 + ln][hi * 8];
        s[nt] = __builtin_amdgcn_mfma_f32_16x16x32_bf16(aq, bk, (f32x4){0.f,0.f,0.f,0.f}, 0, 0, 0);
      }
    }

    // softmax per row, fully in registers (row spread over the 16-lane group)
#pragma unroll
    for (int r = 0; r < 4; ++r) {
      float m = -1e30f;
#pragma unroll
      for (int nt = 0; nt < 4; ++nt) {
        float val = s[nt][r] * SCALE;
        s[nt][r] = val;
        if (nt * 16 + ln < NT) m = fmaxf(m, val);
      }
#pragma unroll
      for (int o = 1; o < 16; o <<= 1) m = fmaxf(m, __shfl_xor(m, o));
      float e[4]; float sum = 0.f;
#pragma unroll
      for (int nt = 0; nt < 4; ++nt) {
        e[nt] = (nt * 16 + ln < NT) ? __expf(s[nt][r] - m) : 0.f;
        sum += e[nt];
      }
#pragma unroll
      for (int o = 1; o < 16; o <<= 1) sum += __shfl_xor(sum, o);
      float inv = 1.f / sum;
      int q = wv * 16 + hi * 4 + r;
#pragma unroll
      for (int nt = 0; nt < 4; ++nt)
        Ps[q][nt * 16 + ln] = f2bf(e[nt] * inv);
    }

    // O^T[d][q] = V^T @ P^T for this wave's q-tile; no barrier needed:
    // each wave reads only Ps rows it wrote (lgkmcnt orders ds_write->ds_read).
    f32x4 o0 = {0.f,0.f,0.f,0.f}, o1 = {0.f,0.f,0.f,0.f};
#pragma unroll
    for (int kb = 0; kb < 2; ++kb) {
      bf16x8 bp  = *(const bf16x8*)&Ps[wv * 16 + ln][kb * 32 + hi * 8];
      bf16x8 av0 = *(const bf16x8*)&Vt[ln][kb * 32 + hi * 8];
      bf16x8 av1 = *(const bf16x8*)&Vt[16 + ln][kb * 32 + hi * 8];
      o0 = __builtin_amdgcn_mfma_f32_16x16x32_bf16(av0, bp, o0, 0, 0, 0);
      o1 = __builtin_amdgcn_mfma_f32_16x16x32_bf16(av1, bp, o1, 0, 0, 0);
    }

    // store: lane holds col q = wv*16+ln, rows d = hi*4+r (o0) / 16+hi*4+r (o1)
    const int q = wv * 16 + ln;
    if (q < NT) {
      const float* xr = x + obase + (size_t)q * C_ + h * HD;
      unsigned short* orow = outA + obase + (size_t)q * C_ + h * HD;
      float4 x0 = *(const float4*)(xr + hi * 4);
      float4 x1 = *(const float4*)(xr + 16 + hi * 4);
      ushort4 r0, r1;
      r0.x = f2bf(o0[0] + x0.x); r0.y = f2bf(o0[1] + x0.y);
      r0.z = f2bf(o0[2] + x0.z); r0.w = f2bf(o0[3] + x0.w);
      r1.x = f2bf(o1[0] + x1.x); r1.y = f2bf(o1[1] + x1.y);
      r1.z = f2bf(o1[2] + x1.z); r1.w = f2bf(o1[3] + x1.w);
      *(ushort4*)(orow + hi * 4) = r0;
      *(ushort4*)(orow + 16 + hi * 4) = r1;
    }
  }
}

// ---- LN + exact GELU on window tokens ----
__global__ __launch_bounds__(64) void ln_gelu_k(
    const unsigned short* __restrict__ outA,
    const float* __restrict__ g, const float* __restrict__ beta,
    unsigned short* __restrict__ wt)
{
  const int row = blockIdx.x;  // 2048 = b*64+w
  const int t = threadIdx.x;
  const size_t base = (size_t)row * NT * C_;  // token 0
  float v[6];
  float s = 0.f, s2 = 0.f;
#pragma unroll
  for (int i = 0; i < 6; ++i) {
    float xv = bf2f(outA[base + t + i * 64]);
    v[i] = xv; s += xv; s2 += xv * xv;
  }
#pragma unroll
  for (int off = 1; off < 64; off <<= 1) {
    s  += __shfl_xor(s, off);
    s2 += __shfl_xor(s2, off);
  }
  const float mu = s * (1.f / 384.f);
  const float var = s2 * (1.f / 384.f) - mu * mu;
  const float rinv = rsqrtf(var + 1e-5f);
#pragma unroll
  for (int i = 0; i < 6; ++i) {
    int c = t + i * 64;
    float y = (v[i] - mu) * rinv * g[c] + beta[c];
    float ge = 0.5f * y * (1.f + erff(y * 0.70710678118654752f));
    wt[(size_t)row * C_ + c] = f2bf(ge);
  }
}

// ---- cross-window pooling attention: pattn[b,h,w,v] ----
__global__ __launch_bounds__(64) void pool_attn_k(
    const float* __restrict__ pqk, float* __restrict__ pattn)
{
  const int h = blockIdx.x;
  const int b = blockIdx.y;
  const int t = threadIdx.x;
  __shared__ float qs[64][32];
  __shared__ float ks[64][32];
  __shared__ float L[64][64];
  for (int idx = t; idx < 64 * 32; idx += 64) {
    int n = idx >> 5, dd = idx & 31;
    int sw = dd ^ (((n >> 3) & 7) << 2);
    size_t base = ((size_t)(b * WN + n)) * (2 * C_) + h * HD + dd;
    qs[n][sw] = pqk[base];
    ks[n][sw] = pqk[base + C_];
  }
  __syncthreads();
  const int ti = t >> 3, tj = t & 7;
  const int i0 = ti << 3, j0 = tj << 3;
  const int swi = ti << 2, swj = tj << 2;
  {
    float acc[8][8];
#pragma unroll
    for (int r = 0; r < 8; ++r)
#pragma unroll
      for (int c = 0; c < 8; ++c) acc[r][c] = 0.f;
#pragma unroll
    for (int d0 = 0; d0 < 32; d0 += 4) {
      float4 qv[8], kv[8];
#pragma unroll
      for (int r = 0; r < 8; ++r) qv[r] = *(const float4*)&qs[i0 + r][d0 ^ swi];
#pragma unroll
      for (int c = 0; c < 8; ++c) kv[c] = *(const float4*)&ks[j0 + c][d0 ^ swj];
#pragma unroll
      for (int r = 0; r < 8; ++r)
#pragma unroll
        for (int c = 0; c < 8; ++c)
          acc[r][c] += qv[r].x * kv[c].x + qv[r].y * kv[c].y + qv[r].z * kv[c].z + qv[r].w * kv[c].w;
    }
#pragma unroll
    for (int r = 0; r < 8; ++r)
#pragma unroll
      for (int c4 = 0; c4 < 2; ++c4) {
        float4 o;
        o.x = acc[r][c4 * 4 + 0] * SCALE; o.y = acc[r][c4 * 4 + 1] * SCALE;
        o.z = acc[r][c4 * 4 + 2] * SCALE; o.w = acc[r][c4 * 4 + 3] * SCALE;
        *(float4*)&L[i0 + r][(j0 + c4 * 4) ^ swi] = o;
      }
  }
  __syncthreads();
  {
    const int sw = (t >> 3) << 2;
    float m = -1e30f;
    for (int j = 0; j < 64; ++j) m = fmaxf(m, L[t][j ^ sw]);
    float sum = 0.f;
    for (int j = 0; j < 64; ++j) { float e = __expf(L[t][j ^ sw] - m); L[t][j ^ sw] = e; sum += e; }
    float inv = 1.f / sum;
    float* dst = pattn + (((size_t)b * NH + h) * 64 + t) * 64;
    for (int j = 0; j < 64; ++j) dst[j] = L[t][j ^ sw] * inv;
  }
}

// ---- pooled SA: psa = pattn @ ax, + ax residual, window->image rearrange, bf16 Y ----
__global__ __launch_bounds__(256) void pool_sa_k(
    const float* __restrict__ pattn,
    const unsigned short* __restrict__ outA,
    unsigned short* __restrict__ Y)
{
  const int tile = blockIdx.x;  // 13 tiles of 128 cols over 49*32=1568
  const int h = blockIdx.y;
  const int b = blockIdx.z;
  const int t = threadIdx.x;
  __shared__ float P[64][65];
  __shared__ float AXT[64][132];
  int limit = 1568 - tile * 128; if (limit > 128) limit = 128;

  {
    const float* src = pattn + ((size_t)b * NH + h) * 4096;
    for (int idx = t; idx < 4096; idx += 256) P[idx >> 6][idx & 63] = src[idx];
  }
  for (int idx = t; idx < 8192; idx += 256) {
    int v = idx >> 7, cc = idx & 127;
    float val = 0.f;
    if (cc < limit) {
      int ch = tile * 128 + cc;
      int s = ch >> 5, dd = ch & 31;
      val = bf2f(outA[((size_t)(b * WN + v) * NT + 1 + s) * C_ + h * HD + dd]);
    }
    AXT[v][cc] = val;
  }
  __syncthreads();

  const int ccq = t & 7;
  const int wi = t >> 3;
  const int w0 = wi, w1 = wi + 32;
  float a0[4][4], a1[4][4];
#pragma unroll
  for (int ch = 0; ch < 4; ++ch)
#pragma unroll
    for (int e = 0; e < 4; ++e) { a0[ch][e] = 0.f; a1[ch][e] = 0.f; }

  for (int v = 0; v < 64; ++v) {
    float p0 = P[w0][v], p1 = P[w1][v];
#pragma unroll
    for (int ch = 0; ch < 4; ++ch) {
      float4 ax = *(const float4*)&AXT[v][ch * 32 + ccq * 4];
      a0[ch][0] += p0 * ax.x; a0[ch][1] += p0 * ax.y; a0[ch][2] += p0 * ax.z; a0[ch][3] += p0 * ax.w;
      a1[ch][0] += p1 * ax.x; a1[ch][1] += p1 * ax.y; a1[ch][2] += p1 * ax.z; a1[ch][3] += p1 * ax.w;
    }
  }
#pragma unroll
  for (int ch = 0; ch < 4; ++ch) {
    int ccb = ch * 32 + ccq * 4;
    if (ccb < limit) {
      int chd = tile * 128 + ccb;
      int s = chd >> 5, dd = chd & 31;
      int srow2 = s / 7, scol = s - srow2 * 7;
      int col = h * HD + dd;
      ushort4 r0, r1;
      r0.x = f2bf(a0[ch][0] + AXT[w0][ccb + 0]);
      r0.y = f2bf(a0[ch][1] + AXT[w0][ccb + 1]);
      r0.z = f2bf(a0[ch][2] + AXT[w0][ccb + 2]);
      r0.w = f2bf(a0[ch][3] + AXT[w0][ccb + 3]);
      r1.x = f2bf(a1[ch][0] + AXT[w1][ccb + 0]);
      r1.y = f2bf(a1[ch][1] + AXT[w1][ccb + 1]);
      r1.z = f2bf(a1[ch][2] + AXT[w1][ccb + 2]);
      r1.w = f2bf(a1[ch][3] + AXT[w1][ccb + 3]);
      int hgi = w0 >> 3, wgi = w0 & 7;
      size_t yi = ((size_t)b * 3136 + (hgi * 7 + srow2) * 56 + wgi * 7 + scol) * C_ + col;
      *(ushort4*)&Y[yi] = r0;
      hgi = w1 >> 3; wgi = w1 & 7;
      yi = ((size_t)b * 3136 + (hgi * 7 + srow2) * 56 + wgi * 7 + scol) * C_ + col;
      *(ushort4*)&Y[yi] = r1;
    }
  }
}

extern "C" void kernel_launch(void* const* d_in, const int* in_sizes, int n_in,
                              void* d_out, int out_size, void* d_ws, size_t ws_size,
                              hipStream_t stream)
{
  (void)in_sizes; (void)n_in; (void)out_size; (void)ws_size;
  const float* x      = (const float*)d_in[0];
  const float* w_qkv  = (const float*)d_in[3];
  const float* w_qk   = (const float*)d_in[4];
  const float* ln_g   = (const float*)d_in[5];
  const float* ln_b   = (const float*)d_in[6];
  const float* w_proj = (const float*)d_in[7];
  const float* b_proj = (const float*)d_in[8];
  float* out = (float*)d_out;

  char* ws = (char*)d_ws;
  size_t off = 0;
  auto alloc = [&](size_t bytes) { size_t o = off; off += (bytes + 255) & ~(size_t)255; return o; };
  const size_t M1 = (size_t)B_ * WN * NT;   // 102400
  const size_t M7 = (size_t)B_ * 3136;      // 100352
  unsigned short* qkv    = (unsigned short*)(ws + alloc(M1 * 1152 * 2));
  unsigned short* xb     = (unsigned short*)(ws + alloc(M1 * C_ * 2));
  unsigned short* outA   = (unsigned short*)(ws + alloc(M1 * C_ * 2));
  unsigned short* wqkvb  = (unsigned short*)(ws + alloc(1152 * 384 * 2));
  unsigned short* wqkb   = (unsigned short*)(ws + alloc(768 * 384 * 2));
  unsigned short* wprojb = (unsigned short*)(ws + alloc(384 * 384 * 2));
  unsigned short* wt     = (unsigned short*)(ws + alloc(2048 * 384 * 2));
  float* pqk             = (float*)(ws + alloc(2048 * 768 * 4));
  float* pattn           = (float*)(ws + alloc((size_t)B_ * NH * 64 * 64 * 4));
  unsigned short* Y = xb;  // xb dead after QKV GEMM

  int q;
  q = (int)(M1 * C_ / 4);
  cvt_bf16_k<<<(q + 255) / 256, 256, 0, stream>>>(x, xb, q);
  q = 1152 * 384 / 4;
  cvt_bf16_k<<<(q + 255) / 256, 256, 0, stream>>>(w_qkv, wqkvb, q);
  q = 768 * 384 / 4;
  cvt_bf16_k<<<(q + 255) / 256, 256, 0, stream>>>(w_qk, wqkb, q);
  q = 384 * 384 / 4;
  cvt_bf16_k<<<(q + 255) / 256, 256, 0, stream>>>(w_proj, wprojb, q);

  // 1) qkv = x @ w_qkv^T  (bf16 out)
  gemm_bf16_k<true, false><<<dim3(1152 / 64, M1 / 64), 256, 0, stream>>>(
      xb, wqkvb, nullptr, qkv, (int)M1, 1152, 384);
  // 2) window attention + residual (MFMA, one block per window)
  attn_win_k<<<dim3(WN, B_), 256, 0, stream>>>(qkv, x, outA);
  // 3) LN + exact GELU on window tokens
  ln_gelu_k<<<2048, 64, 0, stream>>>(outA, ln_g, ln_b, wt);
  // 4) pqk = wt @ w_qk^T (fp32 out)
  gemm_bf16_k<false, false><<<dim3(768 / 64, 2048 / 64), 256, 0, stream>>>(
      wt, wqkb, nullptr, pqk, 2048, 768, 384);
  // 5) cross-window softmax attention
  pool_attn_k<<<dim3(NH, B_), 64, 0, stream>>>(pqk, pattn);
  // 6) psa + ax residual + window->image rearrange (bf16 Y)
  pool_sa_k<<<dim3(13, NH, B_), 256, 0, stream>>>(pattn, outA, Y);
  // 7) out = Y @ w_proj^T + b_proj (fp32)
  gemm_bf16_k<false, true><<<dim3(384 / 64, M7 / 64), 256, 0, stream>>>(
      Y, wprojb, b_proj, out, (int)M7, 384, 384);
}

// Round 3
// 799.431 us; speedup vs baseline: 3.6169x; 1.1265x over previous
//
#include <hip/hip_runtime.h>
#include <cstdint>
#include <cstddef>

#define B_   32
#define WN   64
#define NT   50
#define C_   384
#define NH   12
#define HD   32
#define SCALE 0.17677669529663687f  // 32^-0.5

typedef float  f32x4  __attribute__((ext_vector_type(4)));
typedef __bf16 bf16x8 __attribute__((ext_vector_type(8)));

__device__ __forceinline__ float bf2f(unsigned short u) {
  union { unsigned int u; float f; } v; v.u = ((unsigned int)u) << 16; return v.f;
}
__device__ __forceinline__ unsigned short f2bf(float f) {
  union { float f; unsigned int u; } v; v.f = f;
  unsigned int r = v.u + 0x7FFFu + ((v.u >> 16) & 1u);  // RNE
  return (unsigned short)(r >> 16);
}

__device__ __forceinline__ void gload_lds16(const void* g, void* l) {
  __builtin_amdgcn_global_load_lds(
      (const __attribute__((address_space(1))) void*)g,
      (__attribute__((address_space(3))) void*)l, 16, 0, 0);
}

// ---------------- fp32 -> bf16 conversion ----------------
__global__ __launch_bounds__(256) void cvt_bf16_k(const float* __restrict__ src,
                                                  unsigned short* __restrict__ dst,
                                                  int nquad) {
  int i = blockIdx.x * 256 + threadIdx.x;
  if (i < nquad) {
    float4 v = ((const float4*)src)[i];
    ushort4 o;
    o.x = f2bf(v.x); o.y = f2bf(v.y); o.z = f2bf(v.z); o.w = f2bf(v.w);
    ((ushort4*)dst)[i] = o;
  }
}

// ---- m97-style 128x128 MFMA GEMM: Out[M][N] = A[M][K] @ W[N][K]^T (+bias) ----
// Requires M%128==0, N%128==0, K%32==0. 4 waves, each 64x64 via 4x4 mfma tiles.
// Staging via global_load_lds width=16 (wave-uniform base + lane*16 layout).
template<bool OUT_BF16, bool HAS_BIAS>
__global__ __launch_bounds__(256) void gemm128_k(
    const unsigned short* __restrict__ A,
    const unsigned short* __restrict__ W,
    const float* __restrict__ bias,
    void* __restrict__ Out, int M, int N, int K)
{
  __shared__ unsigned short As[128 * 32];  // 8 KB, 64 B per row (no pad: DMA constraint)
  __shared__ unsigned short Bs[128 * 32];
  const int n0 = blockIdx.x * 128;
  const int m0 = blockIdx.y * 128;
  const int t  = threadIdx.x;
  const int lane = t & 63, wv = t >> 6;
  const int ln = lane & 15, kq = (lane >> 4) << 3;
  const int wm = (wv >> 1) << 6, wn = (wv & 1) << 6;

  // staging geometry: thread t covers tile bytes [t*16, +16) and [4096 + t*16, +16)
  const int row1 = t >> 2;            // 0..63
  const int ce1  = (t & 3) << 3;      // k-element 0/8/16/24
  const size_t arow_a = (size_t)(m0 + row1) * K + ce1;
  const size_t arow_b = (size_t)(n0 + row1) * K + ce1;
  unsigned short* lA0 = As + row1 * 32 + ce1;
  unsigned short* lB0 = Bs + row1 * 32 + ce1;

  f32x4 acc[4][4];
#pragma unroll
  for (int i = 0; i < 4; ++i)
#pragma unroll
    for (int j = 0; j < 4; ++j) acc[i][j] = (f32x4){0.f, 0.f, 0.f, 0.f};

  const int nkb = K >> 5;
  for (int kb = 0; kb < nkb; ++kb) {
    const int k0 = kb << 5;
    if (kb) __syncthreads();  // prior compute's ds_reads complete before overwrite
    gload_lds16(A + arow_a + k0,                 lA0);
    gload_lds16(A + arow_a + (size_t)64 * K + k0, lA0 + 64 * 32);
    gload_lds16(W + arow_b + k0,                 lB0);
    gload_lds16(W + arow_b + (size_t)64 * K + k0, lB0 + 64 * 32);
    __syncthreads();  // compiler drains vmcnt before barrier

    bf16x8 af[4], bf[4];
#pragma unroll
    for (int i = 0; i < 4; ++i) af[i] = *(const bf16x8*)&As[(wm + i * 16 + ln) * 32 + kq];
#pragma unroll
    for (int j = 0; j < 4; ++j) bf[j] = *(const bf16x8*)&Bs[(wn + j * 16 + ln) * 32 + kq];
#pragma unroll
    for (int i = 0; i < 4; ++i)
#pragma unroll
      for (int j = 0; j < 4; ++j)
        acc[i][j] = __builtin_amdgcn_mfma_f32_16x16x32_bf16(af[i], bf[j], acc[i][j], 0, 0, 0);
  }

  const int orow = (lane >> 4) << 2;
#pragma unroll
  for (int i = 0; i < 4; ++i)
#pragma unroll
    for (int j = 0; j < 4; ++j) {
      int gn = n0 + wn + j * 16 + ln;
      float bb = HAS_BIAS ? bias[gn] : 0.f;
#pragma unroll
      for (int r = 0; r < 4; ++r) {
        int gm = m0 + wm + i * 16 + orow + r;
        float v = acc[i][j][r] + bb;
        if (OUT_BF16) ((unsigned short*)Out)[(size_t)gm * N + gn] = f2bf(v);
        else          ((float*)Out)[(size_t)gm * N + gn] = v;
      }
    }
}

// ---- 64x64 MFMA GEMM (kept for the small pqk GEMM) ----
template<bool OUT_BF16, bool HAS_BIAS>
__global__ __launch_bounds__(256) void gemm_bf16_k(
    const unsigned short* __restrict__ A,
    const unsigned short* __restrict__ W,
    const float* __restrict__ bias,
    void* __restrict__ Out, int M, int N, int K)
{
  __shared__ unsigned short As[64][40];
  __shared__ unsigned short Bs[64][40];
  const int n0 = blockIdx.x * 64;
  const int m0 = blockIdx.y * 64;
  const int t  = threadIdx.x;
  const int srow = t >> 2;
  const int sseg = (t & 3) << 3;
  const int lane = t & 63;
  const int wv = t >> 6;
  const int wm = (wv >> 1) << 5;
  const int wn = (wv & 1) << 5;
  const int lr = lane & 15;
  const int kq = (lane >> 4) << 3;

  f32x4 acc[2][2] = {{{0.f,0.f,0.f,0.f},{0.f,0.f,0.f,0.f}},
                     {{0.f,0.f,0.f,0.f},{0.f,0.f,0.f,0.f}}};

  const int nkb = K >> 5;
  for (int kb = 0; kb < nkb; ++kb) {
    const int k0 = kb << 5;
    *(uint4*)&As[srow][sseg] = *(const uint4*)(A + (size_t)(m0 + srow) * K + k0 + sseg);
    *(uint4*)&Bs[srow][sseg] = *(const uint4*)(W + (size_t)(n0 + srow) * K + k0 + sseg);
    __syncthreads();
    bf16x8 a0 = *(const bf16x8*)&As[wm + lr][kq];
    bf16x8 a1 = *(const bf16x8*)&As[wm + 16 + lr][kq];
    bf16x8 b0 = *(const bf16x8*)&Bs[wn + lr][kq];
    bf16x8 b1 = *(const bf16x8*)&Bs[wn + 16 + lr][kq];
    acc[0][0] = __builtin_amdgcn_mfma_f32_16x16x32_bf16(a0, b0, acc[0][0], 0, 0, 0);
    acc[0][1] = __builtin_amdgcn_mfma_f32_16x16x32_bf16(a0, b1, acc[0][1], 0, 0, 0);
    acc[1][0] = __builtin_amdgcn_mfma_f32_16x16x32_bf16(a1, b0, acc[1][0], 0, 0, 0);
    acc[1][1] = __builtin_amdgcn_mfma_f32_16x16x32_bf16(a1, b1, acc[1][1], 0, 0, 0);
    __syncthreads();
  }
  const int orow = (lane >> 4) << 2;
#pragma unroll
  for (int i = 0; i < 2; ++i)
#pragma unroll
    for (int j = 0; j < 2; ++j)
#pragma unroll
      for (int r = 0; r < 4; ++r) {
        int gm = m0 + wm + i * 16 + orow + r;
        int gn = n0 + wn + j * 16 + lr;
        float v = acc[i][j][r];
        if (HAS_BIAS) v += bias[gn];
        if (OUT_BF16) ((unsigned short*)Out)[(size_t)gm * N + gn] = f2bf(v);
        else          ((float*)Out)[(size_t)gm * N + gn] = v;
      }
}

// ---- window attention (MFMA): one block per window, all 12 heads ----
__global__ __launch_bounds__(256) void attn_win_k(
    const unsigned short* __restrict__ qkv,
    const unsigned short* __restrict__ xb,
    unsigned short* __restrict__ outA)
{
  const int w = blockIdx.x, b = blockIdx.y;
  const int t = threadIdx.x;
  const int lane = t & 63, wv = t >> 6;
  const int ln = lane & 15, hi = lane >> 4;

  __shared__ unsigned short Qs[64][40];
  __shared__ unsigned short Ks[64][40];
  __shared__ unsigned short Vt[32][72];
  __shared__ unsigned short Ps[64][72];

  const size_t win = (size_t)(b * WN + w);
  const size_t qkvbase = win * NT * 1152;
  const size_t obase = win * NT * C_;

  for (int h = 0; h < NH; ++h) {
    __syncthreads();
    {
      const int n = t >> 2, seg = (t & 3) << 3;
      uint4 qv = {0,0,0,0}, kv = {0,0,0,0}, vv = {0,0,0,0};
      if (n < NT) {
        const unsigned short* p = qkv + qkvbase + (size_t)n * 1152 + h * HD + seg;
        qv = *(const uint4*)p;
        kv = *(const uint4*)(p + C_);
        vv = *(const uint4*)(p + 2 * C_);
      }
      *(uint4*)&Qs[n][seg] = qv;
      *(uint4*)&Ks[n][seg] = kv;
      const unsigned short* vs = (const unsigned short*)&vv;
#pragma unroll
      for (int j = 0; j < 8; ++j) Vt[seg + j][n] = vs[j];
    }
    __syncthreads();

    f32x4 s[4];
    {
      bf16x8 aq = *(const bf16x8*)&Qs[wv * 16 + ln][hi * 8];
#pragma unroll
      for (int nt = 0; nt < 4; ++nt) {
        bf16x8 bk = *(const bf16x8*)&Ks[nt * 16 + ln][hi * 8];
        s[nt] = __builtin_amdgcn_mfma_f32_16x16x32_bf16(aq, bk, (f32x4){0.f,0.f,0.f,0.f}, 0, 0, 0);
      }
    }

#pragma unroll
    for (int r = 0; r < 4; ++r) {
      float m = -1e30f;
#pragma unroll
      for (int nt = 0; nt < 4; ++nt) {
        float val = s[nt][r] * SCALE;
        s[nt][r] = val;
        if (nt * 16 + ln < NT) m = fmaxf(m, val);
      }
#pragma unroll
      for (int o = 1; o < 16; o <<= 1) m = fmaxf(m, __shfl_xor(m, o));
      float e[4]; float sum = 0.f;
#pragma unroll
      for (int nt = 0; nt < 4; ++nt) {
        e[nt] = (nt * 16 + ln < NT) ? __expf(s[nt][r] - m) : 0.f;
        sum += e[nt];
      }
#pragma unroll
      for (int o = 1; o < 16; o <<= 1) sum += __shfl_xor(sum, o);
      float inv = 1.f / sum;
      int q = wv * 16 + hi * 4 + r;
#pragma unroll
      for (int nt = 0; nt < 4; ++nt)
        Ps[q][nt * 16 + ln] = f2bf(e[nt] * inv);
    }

    f32x4 o0 = {0.f,0.f,0.f,0.f}, o1 = {0.f,0.f,0.f,0.f};
#pragma unroll
    for (int kb = 0; kb < 2; ++kb) {
      bf16x8 bp  = *(const bf16x8*)&Ps[wv * 16 + ln][kb * 32 + hi * 8];
      bf16x8 av0 = *(const bf16x8*)&Vt[ln][kb * 32 + hi * 8];
      bf16x8 av1 = *(const bf16x8*)&Vt[16 + ln][kb * 32 + hi * 8];
      o0 = __builtin_amdgcn_mfma_f32_16x16x32_bf16(av0, bp, o0, 0, 0, 0);
      o1 = __builtin_amdgcn_mfma_f32_16x16x32_bf16(av1, bp, o1, 0, 0, 0);
    }

    const int q = wv * 16 + ln;
    if (q < NT) {
      const unsigned short* xr = xb + obase + (size_t)q * C_ + h * HD;
      unsigned short* orow = outA + obase + (size_t)q * C_ + h * HD;
      ushort4 x0 = *(const ushort4*)(xr + hi * 4);
      ushort4 x1 = *(const ushort4*)(xr + 16 + hi * 4);
      ushort4 r0, r1;
      r0.x = f2bf(o0[0] + bf2f(x0.x)); r0.y = f2bf(o0[1] + bf2f(x0.y));
      r0.z = f2bf(o0[2] + bf2f(x0.z)); r0.w = f2bf(o0[3] + bf2f(x0.w));
      r1.x = f2bf(o1[0] + bf2f(x1.x)); r1.y = f2bf(o1[1] + bf2f(x1.y));
      r1.z = f2bf(o1[2] + bf2f(x1.z)); r1.w = f2bf(o1[3] + bf2f(x1.w));
      *(ushort4*)(orow + hi * 4) = r0;
      *(ushort4*)(orow + 16 + hi * 4) = r1;
    }
  }
}

// ---- LN + exact GELU on window tokens ----
__global__ __launch_bounds__(64) void ln_gelu_k(
    const unsigned short* __restrict__ outA,
    const float* __restrict__ g, const float* __restrict__ beta,
    unsigned short* __restrict__ wt)
{
  const int row = blockIdx.x;
  const int t = threadIdx.x;
  const size_t base = (size_t)row * NT * C_;
  float v[6];
  float s = 0.f, s2 = 0.f;
#pragma unroll
  for (int i = 0; i < 6; ++i) {
    float xv = bf2f(outA[base + t + i * 64]);
    v[i] = xv; s += xv; s2 += xv * xv;
  }
#pragma unroll
  for (int off = 1; off < 64; off <<= 1) {
    s  += __shfl_xor(s, off);
    s2 += __shfl_xor(s2, off);
  }
  const float mu = s * (1.f / 384.f);
  const float var = s2 * (1.f / 384.f) - mu * mu;
  const float rinv = rsqrtf(var + 1e-5f);
#pragma unroll
  for (int i = 0; i < 6; ++i) {
    int c = t + i * 64;
    float y = (v[i] - mu) * rinv * g[c] + beta[c];
    float ge = 0.5f * y * (1.f + erff(y * 0.70710678118654752f));
    wt[(size_t)row * C_ + c] = f2bf(ge);
  }
}

// ---- cross-window pooling attention: pattn[b,h,w,v] ----
__global__ __launch_bounds__(64) void pool_attn_k(
    const float* __restrict__ pqk, float* __restrict__ pattn)
{
  const int h = blockIdx.x;
  const int b = blockIdx.y;
  const int t = threadIdx.x;
  __shared__ float qs[64][32];
  __shared__ float ks[64][32];
  __shared__ float L[64][64];
  for (int idx = t; idx < 64 * 32; idx += 64) {
    int n = idx >> 5, dd = idx & 31;
    int sw = dd ^ (((n >> 3) & 7) << 2);
    size_t base = ((size_t)(b * WN + n)) * (2 * C_) + h * HD + dd;
    qs[n][sw] = pqk[base];
    ks[n][sw] = pqk[base + C_];
  }
  __syncthreads();
  const int ti = t >> 3, tj = t & 7;
  const int i0 = ti << 3, j0 = tj << 3;
  const int swi = ti << 2, swj = tj << 2;
  {
    float acc[8][8];
#pragma unroll
    for (int r = 0; r < 8; ++r)
#pragma unroll
      for (int c = 0; c < 8; ++c) acc[r][c] = 0.f;
#pragma unroll
    for (int d0 = 0; d0 < 32; d0 += 4) {
      float4 qv[8], kv[8];
#pragma unroll
      for (int r = 0; r < 8; ++r) qv[r] = *(const float4*)&qs[i0 + r][d0 ^ swi];
#pragma unroll
      for (int c = 0; c < 8; ++c) kv[c] = *(const float4*)&ks[j0 + c][d0 ^ swj];
#pragma unroll
      for (int r = 0; r < 8; ++r)
#pragma unroll
        for (int c = 0; c < 8; ++c)
          acc[r][c] += qv[r].x * kv[c].x + qv[r].y * kv[c].y + qv[r].z * kv[c].z + qv[r].w * kv[c].w;
    }
#pragma unroll
    for (int r = 0; r < 8; ++r)
#pragma unroll
      for (int c4 = 0; c4 < 2; ++c4) {
        float4 o;
        o.x = acc[r][c4 * 4 + 0] * SCALE; o.y = acc[r][c4 * 4 + 1] * SCALE;
        o.z = acc[r][c4 * 4 + 2] * SCALE; o.w = acc[r][c4 * 4 + 3] * SCALE;
        *(float4*)&L[i0 + r][(j0 + c4 * 4) ^ swi] = o;
      }
  }
  __syncthreads();
  {
    const int sw = (t >> 3) << 2;
    float m = -1e30f;
    for (int j = 0; j < 64; ++j) m = fmaxf(m, L[t][j ^ sw]);
    float sum = 0.f;
    for (int j = 0; j < 64; ++j) { float e = __expf(L[t][j ^ sw] - m); L[t][j ^ sw] = e; sum += e; }
    float inv = 1.f / sum;
    float* dst = pattn + (((size_t)b * NH + h) * 64 + t) * 64;
    for (int j = 0; j < 64; ++j) dst[j] = L[t][j ^ sw] * inv;
  }
}

// ---- pooled SA: psa = pattn @ ax, + ax residual, window->image rearrange, bf16 Y ----
__global__ __launch_bounds__(256) void pool_sa_k(
    const float* __restrict__ pattn,
    const unsigned short* __restrict__ outA,
    unsigned short* __restrict__ Y)
{
  const int tile = blockIdx.x;
  const int h = blockIdx.y;
  const int b = blockIdx.z;
  const int t = threadIdx.x;
  __shared__ float P[64][65];
  __shared__ float AXT[64][132];
  int limit = 1568 - tile * 128; if (limit > 128) limit = 128;

  {
    const float* src = pattn + ((size_t)b * NH + h) * 4096;
    for (int idx = t; idx < 4096; idx += 256) P[idx >> 6][idx & 63] = src[idx];
  }
  for (int idx = t; idx < 8192; idx += 256) {
    int v = idx >> 7, cc = idx & 127;
    float val = 0.f;
    if (cc < limit) {
      int ch = tile * 128 + cc;
      int s = ch >> 5, dd = ch & 31;
      val = bf2f(outA[((size_t)(b * WN + v) * NT + 1 + s) * C_ + h * HD + dd]);
    }
    AXT[v][cc] = val;
  }
  __syncthreads();

  const int ccq = t & 7;
  const int wi = t >> 3;
  const int w0 = wi, w1 = wi + 32;
  float a0[4][4], a1[4][4];
#pragma unroll
  for (int ch = 0; ch < 4; ++ch)
#pragma unroll
    for (int e = 0; e < 4; ++e) { a0[ch][e] = 0.f; a1[ch][e] = 0.f; }

  for (int v = 0; v < 64; ++v) {
    float p0 = P[w0][v], p1 = P[w1][v];
#pragma unroll
    for (int ch = 0; ch < 4; ++ch) {
      float4 ax = *(const float4*)&AXT[v][ch * 32 + ccq * 4];
      a0[ch][0] += p0 * ax.x; a0[ch][1] += p0 * ax.y; a0[ch][2] += p0 * ax.z; a0[ch][3] += p0 * ax.w;
      a1[ch][0] += p1 * ax.x; a1[ch][1] += p1 * ax.y; a1[ch][2] += p1 * ax.z; a1[ch][3] += p1 * ax.w;
    }
  }
#pragma unroll
  for (int ch = 0; ch < 4; ++ch) {
    int ccb = ch * 32 + ccq * 4;
    if (ccb < limit) {
      int chd = tile * 128 + ccb;
      int s = chd >> 5, dd = chd & 31;
      int srow2 = s / 7, scol = s - srow2 * 7;
      int col = h * HD + dd;
      ushort4 r0, r1;
      r0.x = f2bf(a0[ch][0] + AXT[w0][ccb + 0]);
      r0.y = f2bf(a0[ch][1] + AXT[w0][ccb + 1]);
      r0.z = f2bf(a0[ch][2] + AXT[w0][ccb + 2]);
      r0.w = f2bf(a0[ch][3] + AXT[w0][ccb + 3]);
      r1.x = f2bf(a1[ch][0] + AXT[w1][ccb + 0]);
      r1.y = f2bf(a1[ch][1] + AXT[w1][ccb + 1]);
      r1.z = f2bf(a1[ch][2] + AXT[w1][ccb + 2]);
      r1.w = f2bf(a1[ch][3] + AXT[w1][ccb + 3]);
      int hgi = w0 >> 3, wgi = w0 & 7;
      size_t yi = ((size_t)b * 3136 + (hgi * 7 + srow2) * 56 + wgi * 7 + scol) * C_ + col;
      *(ushort4*)&Y[yi] = r0;
      hgi = w1 >> 3; wgi = w1 & 7;
      yi = ((size_t)b * 3136 + (hgi * 7 + srow2) * 56 + wgi * 7 + scol) * C_ + col;
      *(ushort4*)&Y[yi] = r1;
    }
  }
}

extern "C" void kernel_launch(void* const* d_in, const int* in_sizes, int n_in,
                              void* d_out, int out_size, void* d_ws, size_t ws_size,
                              hipStream_t stream)
{
  (void)in_sizes; (void)n_in; (void)out_size; (void)ws_size;
  const float* x      = (const float*)d_in[0];
  const float* w_qkv  = (const float*)d_in[3];
  const float* w_qk   = (const float*)d_in[4];
  const float* ln_g   = (const float*)d_in[5];
  const float* ln_b   = (const float*)d_in[6];
  const float* w_proj = (const float*)d_in[7];
  const float* b_proj = (const float*)d_in[8];
  float* out = (float*)d_out;

  char* ws = (char*)d_ws;
  size_t off = 0;
  auto alloc = [&](size_t bytes) { size_t o = off; off += (bytes + 255) & ~(size_t)255; return o; };
  const size_t M1 = (size_t)B_ * WN * NT;   // 102400
  const size_t M7 = (size_t)B_ * 3136;      // 100352
  unsigned short* qkv    = (unsigned short*)(ws + alloc(M1 * 1152 * 2));
  unsigned short* xb     = (unsigned short*)(ws + alloc(M1 * C_ * 2));
  unsigned short* outA   = (unsigned short*)(ws + alloc(M1 * C_ * 2));
  unsigned short* wqkvb  = (unsigned short*)(ws + alloc(1152 * 384 * 2));
  unsigned short* wqkb   = (unsigned short*)(ws + alloc(768 * 384 * 2));
  unsigned short* wprojb = (unsigned short*)(ws + alloc(384 * 384 * 2));
  unsigned short* wt     = (unsigned short*)(ws + alloc(2048 * 384 * 2));
  float* pqk             = (float*)(ws + alloc(2048 * 768 * 4));
  float* pattn           = (float*)(ws + alloc((size_t)B_ * NH * 64 * 64 * 4));
  unsigned short* Y = xb;  // xb dead after attn_win_k (read there), overwritten by pool_sa_k

  int q;
  q = (int)(M1 * C_ / 4);
  cvt_bf16_k<<<(q + 255) / 256, 256, 0, stream>>>(x, xb, q);
  q = 1152 * 384 / 4;
  cvt_bf16_k<<<(q + 255) / 256, 256, 0, stream>>>(w_qkv, wqkvb, q);
  q = 768 * 384 / 4;
  cvt_bf16_k<<<(q + 255) / 256, 256, 0, stream>>>(w_qk, wqkb, q);
  q = 384 * 384 / 4;
  cvt_bf16_k<<<(q + 255) / 256, 256, 0, stream>>>(w_proj, wprojb, q);

  // 1) qkv = x @ w_qkv^T  (bf16 out) — 128-tile + global_load_lds
  gemm128_k<true, false><<<dim3(1152 / 128, M1 / 128), 256, 0, stream>>>(
      xb, wqkvb, nullptr, qkv, (int)M1, 1152, 384);
  // 2) window attention + residual (MFMA, residual from bf16 xb)
  attn_win_k<<<dim3(WN, B_), 256, 0, stream>>>(qkv, xb, outA);
  // 3) LN + exact GELU on window tokens
  ln_gelu_k<<<2048, 64, 0, stream>>>(outA, ln_g, ln_b, wt);
  // 4) pqk = wt @ w_qk^T (fp32 out) — small, 64-tile for block count
  gemm_bf16_k<false, false><<<dim3(768 / 64, 2048 / 64), 256, 0, stream>>>(
      wt, wqkb, nullptr, pqk, 2048, 768, 384);
  // 5) cross-window softmax attention
  pool_attn_k<<<dim3(NH, B_), 64, 0, stream>>>(pqk, pattn);
  // 6) psa + ax residual + window->image rearrange (bf16 Y)
  pool_sa_k<<<dim3(13, NH, B_), 256, 0, stream>>>(pattn, outA, Y);
  // 7) out = Y @ w_proj^T + b_proj (fp32) — 128-tile + global_load_lds
  gemm128_k<false, true><<<dim3(384 / 128, M7 / 128), 256, 0, stream>>>(
      Y, wprojb, b_proj, out, (int)M7, 384, 384);
}